// Round 2
// baseline (1116.017 us; speedup 1.0000x reference)
//
#include <hip/hip_runtime.h>
#include <hip/hip_bf16.h>
#include <cstdint>

typedef short  bf16x8 __attribute__((ext_vector_type(8)));
typedef float  f32x4  __attribute__((ext_vector_type(4)));
typedef unsigned short u16x8 __attribute__((ext_vector_type(8)));

#define GLDS(gp, lp) __builtin_amdgcn_global_load_lds( \
    (const __attribute__((address_space(1))) void*)(gp), \
    (__attribute__((address_space(3))) void*)(lp), 16, 0, 0)

static constexpr int   MROWS = 16384;   // B*N = 16*1024
static constexpr int   N3    = 3072;    // 3*C
static constexpr float SCALE = 0.125f;  // 8/64

__device__ __forceinline__ unsigned short f2bf(float f) {
  union { float f; unsigned u; } c; c.f = f;
  return (unsigned short)((c.u + 0x7fffu + ((c.u >> 16) & 1u)) >> 16);
}
__device__ __forceinline__ float bf2f(unsigned short h) {
  union { unsigned u; float f; } c; c.u = ((unsigned)h) << 16;
  return c.f;
}
// swap the two 5-bit (h,w) fields within each batch's 1024 rows (involution)
__device__ __forceinline__ int permrow(int m) {
  return (m & ~1023) | ((m & 31) << 5) | ((m >> 5) & 31);
}

// ---- split fp32 activations: row layout [hi(1024) | lo(1024)] bf16 ----
__global__ __launch_bounds__(256) void split_x(const float* __restrict__ src,
                                               unsigned short* __restrict__ dst,
                                               int permute) {
  int idx = blockIdx.x * 256 + threadIdx.x;      // 16384*128 threads, 8 elems each
  int m = idx >> 7, k8 = (idx & 127) << 3;
  int sr = permute ? permrow(m) : m;
  const float* s = src + (size_t)sr * 1024 + k8;
  float4 v0 = *(const float4*)s;
  float4 v1 = *(const float4*)(s + 4);
  float vals[8] = {v0.x, v0.y, v0.z, v0.w, v1.x, v1.y, v1.z, v1.w};
  u16x8 hi, lo;
#pragma unroll
  for (int i = 0; i < 8; ++i) {
    unsigned short h = f2bf(vals[i]);
    hi[i] = h;
    lo[i] = f2bf(vals[i] - bf2f(h));
  }
  unsigned short* d = dst + (size_t)m * 2048 + k8;
  *(u16x8*)(d)        = hi;
  *(u16x8*)(d + 1024) = lo;
}

// ---- split fp32 weights into tripled [hi | lo | hi] bf16 ----
__global__ __launch_bounds__(256) void split_w(const float* __restrict__ src,
                                               unsigned short* __restrict__ dst) {
  int idx = blockIdx.x * 256 + threadIdx.x;      // 3072*128 threads
  int n = idx >> 7, k8 = (idx & 127) << 3;
  const float* s = src + (size_t)n * 1024 + k8;
  float4 v0 = *(const float4*)s;
  float4 v1 = *(const float4*)(s + 4);
  float vals[8] = {v0.x, v0.y, v0.z, v0.w, v1.x, v1.y, v1.z, v1.w};
  u16x8 hi, lo;
#pragma unroll
  for (int i = 0; i < 8; ++i) {
    unsigned short h = f2bf(vals[i]);
    hi[i] = h;
    lo[i] = f2bf(vals[i] - bf2f(h));
  }
  unsigned short* d = dst + (size_t)n * N3 + k8;
  *(u16x8*)(d)        = hi;
  *(u16x8*)(d + 1024) = lo;
  *(u16x8*)(d + 2048) = hi;
}

// ---- C[m][n] = sum over logical K=3072: seg0 Ahi*Bhi, seg1 Ahi*Blo, seg2 Alo*Bhi
// A row layout [hi|lo] stride 2048; B tripled stride 3072. C fp32 (chunk-local).
// 128x128 tile, 4 waves (2x2), BK=32, global_load_lds staging (m97 structure)
__global__ __launch_bounds__(256) void gemm_bt(const unsigned short* __restrict__ A,
                                               const unsigned short* __restrict__ B,
                                               float* __restrict__ C) {
  __shared__ unsigned short As[128 * 32];
  __shared__ unsigned short Bs[128 * 32];
  int tid = threadIdx.x;
  int w = tid >> 6, l = tid & 63;
  int m0 = blockIdx.x * 128, n0 = blockIdx.y * 128;
  int wm = (w >> 1) * 64, wn = (w & 1) * 64;

  // staging: 8 chunks of 1KB per operand tile; wave w owns chunks 2w, 2w+1
  int c0 = w * 2;
  int rA = c0 * 16 + (l >> 2);        // row within tile for this lane
  int kc = (l & 3) * 8;               // k element offset (8 bf16 = 16B)
  const unsigned short* gA0 = A + (size_t)(m0 + rA) * 2048 + kc;
  const unsigned short* gA1 = gA0 + (size_t)16 * 2048;
  const unsigned short* gB0 = B + (size_t)(n0 + rA) * 3072 + kc;
  const unsigned short* gB1 = gB0 + (size_t)16 * 3072;
  unsigned short* lA0 = &As[c0 * 512];
  unsigned short* lA1 = &As[c0 * 512 + 512];
  unsigned short* lB0 = &Bs[c0 * 512];
  unsigned short* lB1 = &Bs[c0 * 512 + 512];

  f32x4 acc[4][4] = {};
  int lr = l & 15, ko = (l >> 4) * 8;

  for (int kt = 0; kt < 3072; kt += 32) {
    if (kt == 1024) { gA0 -= 1024; gA1 -= 1024; }  // seg1 re-reads A-hi
    __syncthreads();                  // previous tile's ds_reads complete
    GLDS(gA0, lA0); GLDS(gA1, lA1);
    GLDS(gB0, lB0); GLDS(gB1, lB1);
    gA0 += 32; gA1 += 32; gB0 += 32; gB1 += 32;
    __syncthreads();                  // staged data visible (vmcnt drained)
    bf16x8 af[4], bb[4];
#pragma unroll
    for (int i = 0; i < 4; ++i)
      af[i] = *(const bf16x8*)&As[(wm + i * 16 + lr) * 32 + ko];
#pragma unroll
    for (int i = 0; i < 4; ++i)
      bb[i] = *(const bf16x8*)&Bs[(wn + i * 16 + lr) * 32 + ko];
#pragma unroll
    for (int i = 0; i < 4; ++i)
#pragma unroll
      for (int j = 0; j < 4; ++j)
        acc[i][j] = __builtin_amdgcn_mfma_f32_16x16x32_bf16(af[i], bb[j], acc[i][j], 0, 0, 0);
  }

  int rq = (l >> 4) * 4;
#pragma unroll
  for (int i = 0; i < 4; ++i)
#pragma unroll
    for (int j = 0; j < 4; ++j) {
      int row = m0 + wm + i * 16 + rq;
      int col = n0 + wn + j * 16 + lr;
      float* cp = C + (size_t)row * N3 + col;
#pragma unroll
      for (int r = 0; r < 4; ++r)
        cp[(size_t)r * N3] = acc[i][j][r];
    }
}

// ---- per (seq, head): LN(q), LN(k), softmax(q*s @ k^T) @ v, fp32 ----
// qkv is chunk-local (rows [mb, mb+mchunk)); out row index is global.
__global__ __launch_bounds__(256) void attn(const float* __restrict__ qkv,
                                            const float* __restrict__ gamma,
                                            const float* __restrict__ beta,
                                            float* __restrict__ out, int permute,
                                            int mb) {
  __shared__ float q[32][65], k[32][65], v[32][65];   // +1 pad: kill bank conflicts
  __shared__ float pr[32][33];
  __shared__ float mu[64], rs[64], gm[64], bt[64];
  int tid = threadIdx.x;
  int s = blockIdx.x >> 4, hd = blockIdx.x & 15;
  size_t base = (size_t)s * 32 * 3072 + hd * 64;
  if (tid < 64) { gm[tid] = gamma[tid]; bt[tid] = beta[tid]; }
  for (int i = tid; i < 2048; i += 256) {
    int p = i >> 6, dd = i & 63;
    size_t r = base + (size_t)p * 3072 + dd;
    q[p][dd] = qkv[r];
    k[p][dd] = qkv[r + 1024];
    v[p][dd] = qkv[r + 2048];
  }
  __syncthreads();
  if (tid < 64) {   // LN stats: rows 0..31 = q, 32..63 = k
    const float* row = (tid < 32) ? q[tid] : k[tid - 32];
    float s1 = 0.f, s2 = 0.f;
    for (int d = 0; d < 64; ++d) { float x = row[d]; s1 += x; s2 += x * x; }
    float m = s1 * 0.015625f;
    float var = s2 * 0.015625f - m * m;
    mu[tid] = m;
    rs[tid] = rsqrtf(var + 1e-5f);
  }
  __syncthreads();
  for (int i = tid; i < 2048; i += 256) {
    int p = i >> 6, dd = i & 63;
    q[p][dd] = ((q[p][dd] - mu[p]) * rs[p] * gm[dd] + bt[dd]) * SCALE;
    k[p][dd] = (k[p][dd] - mu[32 + p]) * rs[32 + p] * gm[dd] + bt[dd];
  }
  __syncthreads();
  for (int i = tid; i < 1024; i += 256) {   // logits
    int r = i >> 5, c = i & 31;
    float a = 0.f;
    for (int d = 0; d < 64; ++d) a += q[r][d] * k[c][d];
    pr[r][c] = a;
  }
  __syncthreads();
  if (tid < 32) {   // softmax rows
    float mx = -1e30f;
    for (int c = 0; c < 32; ++c) mx = fmaxf(mx, pr[tid][c]);
    float sum = 0.f;
    for (int c = 0; c < 32; ++c) { float e = __expf(pr[tid][c] - mx); pr[tid][c] = e; sum += e; }
    float inv = 1.f / sum;
    for (int c = 0; c < 32; ++c) pr[tid][c] *= inv;
  }
  __syncthreads();
  for (int i = tid; i < 2048; i += 256) {   // PV + permuted store
    int p = i >> 6, dd = i & 63;
    float a = 0.f;
    for (int j = 0; j < 32; ++j) a += pr[p][j] * v[j][dd];
    int m = mb + s * 32 + p;                 // global row
    int n = permute ? permrow(m) : m;
    out[(size_t)n * 1024 + hd * 64 + dd] = a;
  }
}

extern "C" void kernel_launch(void* const* d_in, const int* in_sizes, int n_in,
                              void* d_out, int out_size, void* d_ws, size_t ws_size,
                              hipStream_t stream) {
  const float* x    = (const float*)d_in[0];
  const float* Wrow = (const float*)d_in[1];
  const float* Wcol = (const float*)d_in[2];
  const float* grow = (const float*)d_in[3];
  const float* brow = (const float*)d_in[4];
  const float* gcol = (const float*)d_in[5];
  const float* bcol = (const float*)d_in[6];
  float* out = (float*)d_out;

  char* ws = (char*)d_ws;
  const size_t szA2 = (size_t)MROWS * 2048 * 2;   // 67108864
  const size_t szB2 = (size_t)N3 * N3 * 2;        // 18874368
  unsigned short* A2  = (unsigned short*)ws;
  unsigned short* B2  = (unsigned short*)(ws + szA2);
  float*          qkv = (float*)(ws + szA2 + szB2);

  // adaptive M-chunking so A2 + B2 + qkv-chunk fits in ws_size
  int mchunk = MROWS;
  while (mchunk > 128 &&
         szA2 + szB2 + (size_t)mchunk * N3 * 4 > ws_size) mchunk >>= 1;

  for (int pass = 0; pass < 2; ++pass) {
    const float* src = pass ? out : x;
    split_x<<<8192, 256, 0, stream>>>(src, A2, pass);
    split_w<<<1536, 256, 0, stream>>>(pass ? Wcol : Wrow, B2);
    for (int mbase = 0; mbase < MROWS; mbase += mchunk) {
      dim3 gGemm(mchunk / 128, N3 / 128);
      gemm_bt<<<gGemm, 256, 0, stream>>>(A2 + (size_t)mbase * 2048, B2, qkv);
      attn<<<(mchunk / 32) * 16, 256, 0, stream>>>(
          qkv, pass ? gcol : grow, pass ? bcol : brow, out, pass, mbase);
    }
  }
}

// Round 3
// 903.780 us; speedup vs baseline: 1.2348x; 1.2348x over previous
//
#include <hip/hip_runtime.h>
#include <hip/hip_bf16.h>
#include <cstdint>

typedef short  bf16x8 __attribute__((ext_vector_type(8)));
typedef float  f32x4  __attribute__((ext_vector_type(4)));
typedef unsigned short u16x8 __attribute__((ext_vector_type(8)));

#define GLDS(gp, lp) __builtin_amdgcn_global_load_lds( \
    (const __attribute__((address_space(1))) void*)(gp), \
    (__attribute__((address_space(3))) void*)(lp), 16, 0, 0)

static constexpr int   MROWS = 16384;   // B*N = 16*1024
static constexpr int   N3    = 3072;    // 3*C
static constexpr int   NT    = 48;      // K-tiles of 64 (logical K = 3072)
static constexpr float SCALE = 0.125f;  // 8/64

__device__ __forceinline__ unsigned short f2bf(float f) {
  union { float f; unsigned u; } c; c.f = f;
  return (unsigned short)((c.u + 0x7fffu + ((c.u >> 16) & 1u)) >> 16);
}
__device__ __forceinline__ float bf2f(unsigned short h) {
  union { unsigned u; float f; } c; c.u = ((unsigned)h) << 16;
  return c.f;
}
// swap the two 5-bit (h,w) fields within each batch's 1024 rows (involution)
__device__ __forceinline__ int permrow(int m) {
  return (m & ~1023) | ((m & 31) << 5) | ((m >> 5) & 31);
}

// ---- split fp32 activations: row layout [hi(1024) | lo(1024)] bf16 ----
__global__ __launch_bounds__(256) void split_x(const float* __restrict__ src,
                                               unsigned short* __restrict__ dst,
                                               int permute) {
  int idx = blockIdx.x * 256 + threadIdx.x;
  int m = idx >> 7, k8 = (idx & 127) << 3;
  int sr = permute ? permrow(m) : m;
  const float* s = src + (size_t)sr * 1024 + k8;
  float4 v0 = *(const float4*)s;
  float4 v1 = *(const float4*)(s + 4);
  float vals[8] = {v0.x, v0.y, v0.z, v0.w, v1.x, v1.y, v1.z, v1.w};
  u16x8 hi, lo;
#pragma unroll
  for (int i = 0; i < 8; ++i) {
    unsigned short h = f2bf(vals[i]);
    hi[i] = h;
    lo[i] = f2bf(vals[i] - bf2f(h));
  }
  unsigned short* d = dst + (size_t)m * 2048 + k8;
  *(u16x8*)(d)        = hi;
  *(u16x8*)(d + 1024) = lo;
}

// ---- split fp32 weights into tripled [hi | lo | hi] bf16 ----
__global__ __launch_bounds__(256) void split_w(const float* __restrict__ src,
                                               unsigned short* __restrict__ dst) {
  int idx = blockIdx.x * 256 + threadIdx.x;
  int n = idx >> 7, k8 = (idx & 127) << 3;
  const float* s = src + (size_t)n * 1024 + k8;
  float4 v0 = *(const float4*)s;
  float4 v1 = *(const float4*)(s + 4);
  float vals[8] = {v0.x, v0.y, v0.z, v0.w, v1.x, v1.y, v1.z, v1.w};
  u16x8 hi, lo;
#pragma unroll
  for (int i = 0; i < 8; ++i) {
    unsigned short h = f2bf(vals[i]);
    hi[i] = h;
    lo[i] = f2bf(vals[i] - bf2f(h));
  }
  unsigned short* d = dst + (size_t)n * N3 + k8;
  *(u16x8*)(d)        = hi;
  *(u16x8*)(d + 1024) = lo;
  *(u16x8*)(d + 2048) = hi;
}

// ================= 256x256 8-wave GEMM, 4-phase/K-tile counted-vmcnt ======
// C[m][n] = sum over logical K=3072: seg0 Ahi*Bhi, seg1 Ahi*Blo, seg2 Alo*Bhi
// A row layout [hi|lo] stride 2048 (rewind at K-tile 16); B tripled stride 3072.
// LDS: 2 bufs x (A 32KB + B 32KB) = 128 KB, subtiled [16r x 32k] (1024 B) with
// st_16x32 XOR swizzle (byte ^= ((byte>>9)&1)<<5 within subtile), staged via
// linear global_load_lds dest + inverse-swizzled per-lane global source.
__global__ __launch_bounds__(512, 2) void gemm256(const unsigned short* __restrict__ A,
                                                  const unsigned short* __restrict__ Bm,
                                                  unsigned short* __restrict__ Cq) {
  __shared__ unsigned char smem[131072];
  const int tid = threadIdx.x;
  const int w = tid >> 6, l = tid & 63;
  const int wr = w >> 2, wc = w & 3;          // 2 x 4 wave grid

  // XCD-aware swizzle (768 blocks, 768 % 8 == 0 -> simple bijective form)
  const int bid = blockIdx.x;
  const int swz = (bid & 7) * 96 + (bid >> 3);
  const int m0 = (swz & 63) << 8;             // 64 m-tiles (fast: share B panel)
  const int n0 = (swz >> 6) << 8;             // 12 n-tiles

  // staging: wave w owns row-groups R=2w,2w+1 of each 16KB K-half unit.
  // lane l -> row R*16 + (l>>2), k elem C*32 + ((l&3)*8 ^ (l>=32 ? 16 : 0))
  const int ske = ((l & 3) * 8) ^ ((l >= 32) ? 16 : 0);
  const unsigned short* gA0 = A  + (size_t)(m0 + w * 32 + (l >> 2)) * 2048 + ske;
  const unsigned short* gA1 = gA0 + 16 * 2048;
  const unsigned short* gB0 = Bm + (size_t)(n0 + w * 32 + (l >> 2)) * 3072 + ske;
  const unsigned short* gB1 = gB0 + (size_t)16 * 3072;
  int kA = 0, kB = 0;                         // k-elem offset of K-tile being staged

  // swizzled ds_read lane offset (16B frag at row lr, k-group ko)
  const int lr = l & 15;
  const int laneoff = ((lr * 64) + ((l >> 4) * 16)) ^ ((lr & 8) << 2);

#define STAGE_A(pb, C) do { \
    GLDS(gA0 + kA + (C) * 32, smem + (pb) * 65536 + (4 * w + (C)) * 1024); \
    GLDS(gA1 + kA + (C) * 32, smem + (pb) * 65536 + (4 * w + 2 + (C)) * 1024); } while (0)
#define STAGE_B(pb, C) do { \
    GLDS(gB0 + kB + (C) * 32, smem + (pb) * 65536 + 32768 + (4 * w + (C)) * 1024); \
    GLDS(gB1 + kB + (C) * 32, smem + (pb) * 65536 + 32768 + (4 * w + 2 + (C)) * 1024); } while (0)
#define MFMA(af, bf, c) __builtin_amdgcn_mfma_f32_16x16x32_bf16(af, bf, c, 0, 0, 0)

  f32x4 acc[8][4] = {};

  // ---- prologue: stage K-tile 0 fully; kk0 halves drained ----
  STAGE_A(0, 0); STAGE_B(0, 0); STAGE_A(0, 1); STAGE_B(0, 1);
  kA = 64; kB = 64;
  asm volatile("s_waitcnt vmcnt(4)" ::: "memory");
  __builtin_amdgcn_s_barrier();

  for (int t = 0; t < NT; ++t) {
    const int p = t & 1, q = p ^ 1;
    const unsigned char* rb = smem + p * 65536;
    bf16x8 a[8], b0, b1, b2, b3;

    // ---------- phase 1: kk0, ni 0-1 ----------
#pragma unroll
    for (int mi = 0; mi < 8; ++mi)
      a[mi] = *(const bf16x8*)(rb + (wr * 8 + mi) * 2048 + laneoff);
    b0 = *(const bf16x8*)(rb + 32768 + (wc * 4 + 0) * 2048 + laneoff);
    b1 = *(const bf16x8*)(rb + 32768 + (wc * 4 + 1) * 2048 + laneoff);
    if (t < NT - 1) STAGE_A(q, 0);
    __builtin_amdgcn_s_barrier();
    asm volatile("s_waitcnt lgkmcnt(0)" ::: "memory");
    __builtin_amdgcn_sched_barrier(0);
    __builtin_amdgcn_s_setprio(1);
#pragma unroll
    for (int mi = 0; mi < 8; ++mi) {
      acc[mi][0] = MFMA(a[mi], b0, acc[mi][0]);
      acc[mi][1] = MFMA(a[mi], b1, acc[mi][1]);
    }
    __builtin_amdgcn_s_setprio(0);
    __builtin_amdgcn_s_barrier();

    // ---------- phase 2: kk0, ni 2-3 ----------
    b2 = *(const bf16x8*)(rb + 32768 + (wc * 4 + 2) * 2048 + laneoff);
    b3 = *(const bf16x8*)(rb + 32768 + (wc * 4 + 3) * 2048 + laneoff);
    if (t < NT - 1) STAGE_B(q, 0);
    __builtin_amdgcn_s_barrier();
    asm volatile("s_waitcnt lgkmcnt(0)" ::: "memory");
    __builtin_amdgcn_sched_barrier(0);
    __builtin_amdgcn_s_setprio(1);
#pragma unroll
    for (int mi = 0; mi < 8; ++mi) {
      acc[mi][2] = MFMA(a[mi], b2, acc[mi][2]);
      acc[mi][3] = MFMA(a[mi], b3, acc[mi][3]);
    }
    __builtin_amdgcn_s_setprio(0);
    // ensure this K-tile's kk1 halves (staged 2 phases ago) have landed
    if (t < NT - 1) { asm volatile("s_waitcnt vmcnt(4)" ::: "memory"); }
    else            { asm volatile("s_waitcnt vmcnt(0)" ::: "memory"); }
    __builtin_amdgcn_s_barrier();

    // ---------- phase 3: kk1, ni 0-1 ----------
#pragma unroll
    for (int mi = 0; mi < 8; ++mi)
      a[mi] = *(const bf16x8*)(rb + (wr * 8 + mi) * 2048 + 1024 + laneoff);
    b0 = *(const bf16x8*)(rb + 32768 + (wc * 4 + 0) * 2048 + 1024 + laneoff);
    b1 = *(const bf16x8*)(rb + 32768 + (wc * 4 + 1) * 2048 + 1024 + laneoff);
    if (t < NT - 1) STAGE_A(q, 1);
    __builtin_amdgcn_s_barrier();
    asm volatile("s_waitcnt lgkmcnt(0)" ::: "memory");
    __builtin_amdgcn_sched_barrier(0);
    __builtin_amdgcn_s_setprio(1);
#pragma unroll
    for (int mi = 0; mi < 8; ++mi) {
      acc[mi][0] = MFMA(a[mi], b0, acc[mi][0]);
      acc[mi][1] = MFMA(a[mi], b1, acc[mi][1]);
    }
    __builtin_amdgcn_s_setprio(0);
    __builtin_amdgcn_s_barrier();

    // ---------- phase 4: kk1, ni 2-3 ----------
    b2 = *(const bf16x8*)(rb + 32768 + (wc * 4 + 2) * 2048 + 1024 + laneoff);
    b3 = *(const bf16x8*)(rb + 32768 + (wc * 4 + 3) * 2048 + 1024 + laneoff);
    if (t < NT - 1) STAGE_B(q, 1);
    __builtin_amdgcn_s_barrier();
    asm volatile("s_waitcnt lgkmcnt(0)" ::: "memory");
    __builtin_amdgcn_sched_barrier(0);
    __builtin_amdgcn_s_setprio(1);
#pragma unroll
    for (int mi = 0; mi < 8; ++mi) {
      acc[mi][2] = MFMA(a[mi], b2, acc[mi][2]);
      acc[mi][3] = MFMA(a[mi], b3, acc[mi][3]);
    }
    __builtin_amdgcn_s_setprio(0);
    // next K-tile's kk0 halves (staged phases 1-2) must land before next iter
    asm volatile("s_waitcnt vmcnt(4)" ::: "memory");
    __builtin_amdgcn_s_barrier();

    kB += 64;
    kA += 64; if (t == 14) kA -= 1024;   // hi-segment rewind: phys(16) = 0
  }

  // ---- epilogue: acc -> bf16 C ----
  const int rq = (l >> 4) * 4;
#pragma unroll
  for (int mi = 0; mi < 8; ++mi)
#pragma unroll
    for (int ni = 0; ni < 4; ++ni) {
      int row = m0 + wr * 128 + mi * 16 + rq;
      int col = n0 + wc * 64 + ni * 16 + lr;
      unsigned short* cp = Cq + (size_t)row * N3 + col;
#pragma unroll
      for (int r = 0; r < 4; ++r)
        cp[(size_t)r * N3] = f2bf(acc[mi][ni][r]);
    }
#undef STAGE_A
#undef STAGE_B
#undef MFMA
}

// ---- per (seq, head): LN(q), LN(k), softmax(q*s @ k^T) @ v; bf16 in, f32 out
__global__ __launch_bounds__(256) void attn(const unsigned short* __restrict__ qkv,
                                            const float* __restrict__ gamma,
                                            const float* __restrict__ beta,
                                            float* __restrict__ out, int permute) {
  __shared__ float q[32][65], k[32][65], v[32][65];
  __shared__ float pr[32][33];
  __shared__ float mu[64], rs[64], gm[64], bt[64];
  const int tid = threadIdx.x;
  const int s = blockIdx.x >> 4, hd = blockIdx.x & 15;
  const size_t base = (size_t)s * 32 * 3072 + hd * 64;
  if (tid < 64) { gm[tid] = gamma[tid]; bt[tid] = beta[tid]; }
  {
    const int p = tid >> 3, d0 = (tid & 7) * 8;
    size_t r = base + (size_t)p * 3072 + d0;
    u16x8 qa = *(const u16x8*)(qkv + r);
    u16x8 ka = *(const u16x8*)(qkv + r + 1024);
    u16x8 va = *(const u16x8*)(qkv + r + 2048);
#pragma unroll
    for (int j = 0; j < 8; ++j) {
      q[p][d0 + j] = bf2f(qa[j]);
      k[p][d0 + j] = bf2f(ka[j]);
      v[p][d0 + j] = bf2f(va[j]);
    }
  }
  __syncthreads();
  {  // LN stats: 64 rows (q 0-31, k 32-63) x 4 threads each
    const int r = tid >> 2, qt = tid & 3;
    const float* row = (r < 32) ? q[r] : k[r - 32];
    float s1 = 0.f, s2 = 0.f;
#pragma unroll
    for (int d = qt * 16; d < qt * 16 + 16; ++d) { float x = row[d]; s1 += x; s2 += x * x; }
    s1 += __shfl_xor(s1, 1); s2 += __shfl_xor(s2, 1);
    s1 += __shfl_xor(s1, 2); s2 += __shfl_xor(s2, 2);
    if (qt == 0) {
      float m = s1 * 0.015625f;
      mu[r] = m;
      rs[r] = rsqrtf(s2 * 0.015625f - m * m + 1e-5f);
    }
  }
  __syncthreads();
  {
    const int p = tid >> 3, d0 = (tid & 7) * 8;
#pragma unroll
    for (int j = 0; j < 8; ++j) {
      int d = d0 + j;
      q[p][d] = ((q[p][d] - mu[p]) * rs[p] * gm[d] + bt[d]) * SCALE;
      k[p][d] = (k[p][d] - mu[32 + p]) * rs[32 + p] * gm[d] + bt[d];
    }
  }
  __syncthreads();
  {  // logits: 4 per thread
    const int r = tid >> 3, c0 = (tid & 7) * 4;
#pragma unroll
    for (int cc = 0; cc < 4; ++cc) {
      float a = 0.f;
      const float* qr = q[r]; const float* kr = k[c0 + cc];
#pragma unroll
      for (int d = 0; d < 64; ++d) a += qr[d] * kr[d];
      pr[r][c0 + cc] = a;
    }
  }
  __syncthreads();
  {  // softmax: 8 threads per row
    const int r = tid >> 3, c0 = (tid & 7) * 4;
    float e0 = pr[r][c0], e1 = pr[r][c0 + 1], e2 = pr[r][c0 + 2], e3 = pr[r][c0 + 3];
    float mx = fmaxf(fmaxf(e0, e1), fmaxf(e2, e3));
    mx = fmaxf(mx, __shfl_xor(mx, 1));
    mx = fmaxf(mx, __shfl_xor(mx, 2));
    mx = fmaxf(mx, __shfl_xor(mx, 4));
    e0 = __expf(e0 - mx); e1 = __expf(e1 - mx);
    e2 = __expf(e2 - mx); e3 = __expf(e3 - mx);
    float sum = e0 + e1 + e2 + e3;
    sum += __shfl_xor(sum, 1);
    sum += __shfl_xor(sum, 2);
    sum += __shfl_xor(sum, 4);
    float inv = 1.f / sum;
    pr[r][c0] = e0 * inv; pr[r][c0 + 1] = e1 * inv;
    pr[r][c0 + 2] = e2 * inv; pr[r][c0 + 3] = e3 * inv;
  }
  __syncthreads();
  {  // PV + permuted store
    const int p = tid >> 3, d0 = (tid & 7) * 8;
    float o[8] = {};
#pragma unroll
    for (int j = 0; j < 32; ++j) {
      float pj = pr[p][j];
#pragma unroll
      for (int d = 0; d < 8; ++d) o[d] += pj * v[j][d0 + d];
    }
    int m = s * 32 + p;
    int n = permute ? permrow(m) : m;
    float* op = out + (size_t)n * 1024 + hd * 64 + d0;
#pragma unroll
    for (int d = 0; d < 8; ++d) op[d] = o[d];
  }
}

extern "C" void kernel_launch(void* const* d_in, const int* in_sizes, int n_in,
                              void* d_out, int out_size, void* d_ws, size_t ws_size,
                              hipStream_t stream) {
  const float* x    = (const float*)d_in[0];
  const float* Wrow = (const float*)d_in[1];
  const float* Wcol = (const float*)d_in[2];
  const float* grow = (const float*)d_in[3];
  const float* brow = (const float*)d_in[4];
  const float* gcol = (const float*)d_in[5];
  const float* bcol = (const float*)d_in[6];
  float* out = (float*)d_out;

  char* ws = (char*)d_ws;
  const size_t szA2 = (size_t)MROWS * 2048 * 2;   // 67108864
  const size_t szB2 = (size_t)N3 * N3 * 2;        // 18874368
  unsigned short* A2   = (unsigned short*)ws;
  unsigned short* B2   = (unsigned short*)(ws + szA2);
  unsigned short* qkvb = (unsigned short*)(ws + szA2 + szB2);  // 16384*3072*2 = 100663296
  // total 186646528 B == round-2's proven-fitting requirement

  for (int pass = 0; pass < 2; ++pass) {
    const float* src = pass ? out : x;
    split_x<<<8192, 256, 0, stream>>>(src, A2, pass);
    split_w<<<1536, 256, 0, stream>>>(pass ? Wcol : Wrow, B2);
    gemm256<<<768, 512, 0, stream>>>(A2, B2, qkvb);
    attn<<<8192, 256, 0, stream>>>(qkvb, pass ? gcol : grow, pass ? bcol : brow, out, pass);
  }
}

// Round 4
// 887.587 us; speedup vs baseline: 1.2574x; 1.0182x over previous
//
#include <hip/hip_runtime.h>
#include <hip/hip_bf16.h>
#include <cstdint>

typedef short  bf16x8 __attribute__((ext_vector_type(8)));
typedef float  f32x4  __attribute__((ext_vector_type(4)));
typedef unsigned short u16x8 __attribute__((ext_vector_type(8)));

#define GLDS(gp, lp) __builtin_amdgcn_global_load_lds( \
    (const __attribute__((address_space(1))) void*)(gp), \
    (__attribute__((address_space(3))) void*)(lp), 16, 0, 0)

static constexpr int   MROWS = 16384;   // B*N = 16*1024
static constexpr int   N3    = 3072;    // 3*C
static constexpr int   NT    = 48;      // K-tiles of 64 (logical K = 3072)
static constexpr float SCALE = 0.125f;  // 8/64

__device__ __forceinline__ unsigned short f2bf(float f) {
  union { float f; unsigned u; } c; c.f = f;
  return (unsigned short)((c.u + 0x7fffu + ((c.u >> 16) & 1u)) >> 16);
}
__device__ __forceinline__ float bf2f(unsigned short h) {
  union { unsigned u; float f; } c; c.u = ((unsigned)h) << 16;
  return c.f;
}
// swap the two 5-bit (h,w) fields within each batch's 1024 rows (involution)
__device__ __forceinline__ int permrow(int m) {
  return (m & ~1023) | ((m & 31) << 5) | ((m >> 5) & 31);
}

// ---- split fp32 activations: row layout [hi(1024) | lo(1024)] bf16 ----
__global__ __launch_bounds__(256) void split_x(const float* __restrict__ src,
                                               unsigned short* __restrict__ dst) {
  int idx = blockIdx.x * 256 + threadIdx.x;
  int m = idx >> 7, k8 = (idx & 127) << 3;
  const float* s = src + (size_t)m * 1024 + k8;
  float4 v0 = *(const float4*)s;
  float4 v1 = *(const float4*)(s + 4);
  float vals[8] = {v0.x, v0.y, v0.z, v0.w, v1.x, v1.y, v1.z, v1.w};
  u16x8 hi, lo;
#pragma unroll
  for (int i = 0; i < 8; ++i) {
    unsigned short h = f2bf(vals[i]);
    hi[i] = h;
    lo[i] = f2bf(vals[i] - bf2f(h));
  }
  unsigned short* d = dst + (size_t)m * 2048 + k8;
  *(u16x8*)(d)        = hi;
  *(u16x8*)(d + 1024) = lo;
}

// ---- split fp32 weights into tripled [hi | lo | hi] bf16 ----
__global__ __launch_bounds__(256) void split_w(const float* __restrict__ src,
                                               unsigned short* __restrict__ dst) {
  int idx = blockIdx.x * 256 + threadIdx.x;
  int n = idx >> 7, k8 = (idx & 127) << 3;
  const float* s = src + (size_t)n * 1024 + k8;
  float4 v0 = *(const float4*)s;
  float4 v1 = *(const float4*)(s + 4);
  float vals[8] = {v0.x, v0.y, v0.z, v0.w, v1.x, v1.y, v1.z, v1.w};
  u16x8 hi, lo;
#pragma unroll
  for (int i = 0; i < 8; ++i) {
    unsigned short h = f2bf(vals[i]);
    hi[i] = h;
    lo[i] = f2bf(vals[i] - bf2f(h));
  }
  unsigned short* d = dst + (size_t)n * N3 + k8;
  *(u16x8*)(d)        = hi;
  *(u16x8*)(d + 1024) = lo;
  *(u16x8*)(d + 2048) = hi;
}

// ================= 256x256 8-wave GEMM, 4-phase/K-tile counted-vmcnt ======
// C[m][n] = sum over logical K=3072: seg0 Ahi*Bhi, seg1 Ahi*Blo, seg2 Alo*Bhi
// A row layout [hi|lo] stride 2048 (rewind at K-tile 16); B tripled stride 3072.
// LDS: 2 bufs x (A 32KB + B 32KB) = 128 KB, subtiled [16r x 32k] (1024 B) with
// st_16x32 XOR swizzle, staged via linear global_load_lds dest +
// inverse-swizzled per-lane global source.
// Grid order: n fast (12 consecutive blocks share one A m-panel -> LLC reads A once).
__global__ __launch_bounds__(512, 2) void gemm256(const unsigned short* __restrict__ A,
                                                  const unsigned short* __restrict__ Bm,
                                                  unsigned short* __restrict__ Cq) {
  __shared__ unsigned char smem[131072];
  const int tid = threadIdx.x;
  const int w = tid >> 6, l = tid & 63;
  const int wr = w >> 2, wc = w & 3;          // 2 x 4 wave grid

  const int bid = blockIdx.x;
  const int m0 = (bid / 12) << 8;             // slow: 64 m-tiles
  const int n0 = (bid % 12) << 8;             // fast: 12 n-tiles

  // staging: wave w owns row-groups R=2w,2w+1 of each 16KB K-half unit.
  const int ske = ((l & 3) * 8) ^ ((l >= 32) ? 16 : 0);
  const unsigned short* gA0 = A  + (size_t)(m0 + w * 32 + (l >> 2)) * 2048 + ske;
  const unsigned short* gA1 = gA0 + 16 * 2048;
  const unsigned short* gB0 = Bm + (size_t)(n0 + w * 32 + (l >> 2)) * 3072 + ske;
  const unsigned short* gB1 = gB0 + (size_t)16 * 3072;
  int kA = 0, kB = 0;                         // k-elem offset of K-tile being staged

  // swizzled ds_read lane offset (16B frag at row lr, k-group ko)
  const int lr = l & 15;
  const int laneoff = ((lr * 64) + ((l >> 4) * 16)) ^ ((lr & 8) << 2);

#define STAGE_A(pb, C) do { \
    GLDS(gA0 + kA + (C) * 32, smem + (pb) * 65536 + (4 * w + (C)) * 1024); \
    GLDS(gA1 + kA + (C) * 32, smem + (pb) * 65536 + (4 * w + 2 + (C)) * 1024); } while (0)
#define STAGE_B(pb, C) do { \
    GLDS(gB0 + kB + (C) * 32, smem + (pb) * 65536 + 32768 + (4 * w + (C)) * 1024); \
    GLDS(gB1 + kB + (C) * 32, smem + (pb) * 65536 + 32768 + (4 * w + 2 + (C)) * 1024); } while (0)
#define MFMA(af, bf, c) __builtin_amdgcn_mfma_f32_16x16x32_bf16(af, bf, c, 0, 0, 0)

  f32x4 acc[8][4] = {};

  // ---- prologue: stage K-tile 0 fully; kk0 halves drained ----
  STAGE_A(0, 0); STAGE_B(0, 0); STAGE_A(0, 1); STAGE_B(0, 1);
  kA = 64; kB = 64;
  asm volatile("s_waitcnt vmcnt(4)" ::: "memory");
  __builtin_amdgcn_s_barrier();

  for (int t = 0; t < NT; ++t) {
    const int p = t & 1, q = p ^ 1;
    const unsigned char* rb = smem + p * 65536;
    bf16x8 a[8], b0, b1, b2, b3;

    // ---------- phase 1: kk0, ni 0-1 ----------
#pragma unroll
    for (int mi = 0; mi < 8; ++mi)
      a[mi] = *(const bf16x8*)(rb + (wr * 8 + mi) * 2048 + laneoff);
    b0 = *(const bf16x8*)(rb + 32768 + (wc * 4 + 0) * 2048 + laneoff);
    b1 = *(const bf16x8*)(rb + 32768 + (wc * 4 + 1) * 2048 + laneoff);
    if (t < NT - 1) STAGE_A(q, 0);
    __builtin_amdgcn_s_barrier();
    asm volatile("s_waitcnt lgkmcnt(0)" ::: "memory");
    __builtin_amdgcn_sched_barrier(0);
    __builtin_amdgcn_s_setprio(1);
#pragma unroll
    for (int mi = 0; mi < 8; ++mi) {
      acc[mi][0] = MFMA(a[mi], b0, acc[mi][0]);
      acc[mi][1] = MFMA(a[mi], b1, acc[mi][1]);
    }
    __builtin_amdgcn_s_setprio(0);
    __builtin_amdgcn_s_barrier();

    // ---------- phase 2: kk0, ni 2-3 ----------
    b2 = *(const bf16x8*)(rb + 32768 + (wc * 4 + 2) * 2048 + laneoff);
    b3 = *(const bf16x8*)(rb + 32768 + (wc * 4 + 3) * 2048 + laneoff);
    if (t < NT - 1) STAGE_B(q, 0);
    __builtin_amdgcn_s_barrier();
    asm volatile("s_waitcnt lgkmcnt(0)" ::: "memory");
    __builtin_amdgcn_sched_barrier(0);
    __builtin_amdgcn_s_setprio(1);
#pragma unroll
    for (int mi = 0; mi < 8; ++mi) {
      acc[mi][2] = MFMA(a[mi], b2, acc[mi][2]);
      acc[mi][3] = MFMA(a[mi], b3, acc[mi][3]);
    }
    __builtin_amdgcn_s_setprio(0);
    if (t < NT - 1) { asm volatile("s_waitcnt vmcnt(4)" ::: "memory"); }
    else            { asm volatile("s_waitcnt vmcnt(0)" ::: "memory"); }
    __builtin_amdgcn_s_barrier();

    // ---------- phase 3: kk1, ni 0-1 ----------
#pragma unroll
    for (int mi = 0; mi < 8; ++mi)
      a[mi] = *(const bf16x8*)(rb + (wr * 8 + mi) * 2048 + 1024 + laneoff);
    b0 = *(const bf16x8*)(rb + 32768 + (wc * 4 + 0) * 2048 + 1024 + laneoff);
    b1 = *(const bf16x8*)(rb + 32768 + (wc * 4 + 1) * 2048 + 1024 + laneoff);
    if (t < NT - 1) STAGE_A(q, 1);
    __builtin_amdgcn_s_barrier();
    asm volatile("s_waitcnt lgkmcnt(0)" ::: "memory");
    __builtin_amdgcn_sched_barrier(0);
    __builtin_amdgcn_s_setprio(1);
#pragma unroll
    for (int mi = 0; mi < 8; ++mi) {
      acc[mi][0] = MFMA(a[mi], b0, acc[mi][0]);
      acc[mi][1] = MFMA(a[mi], b1, acc[mi][1]);
    }
    __builtin_amdgcn_s_setprio(0);
    __builtin_amdgcn_s_barrier();

    // ---------- phase 4: kk1, ni 2-3 ----------
    b2 = *(const bf16x8*)(rb + 32768 + (wc * 4 + 2) * 2048 + 1024 + laneoff);
    b3 = *(const bf16x8*)(rb + 32768 + (wc * 4 + 3) * 2048 + 1024 + laneoff);
    if (t < NT - 1) STAGE_B(q, 1);
    __builtin_amdgcn_s_barrier();
    asm volatile("s_waitcnt lgkmcnt(0)" ::: "memory");
    __builtin_amdgcn_sched_barrier(0);
    __builtin_amdgcn_s_setprio(1);
#pragma unroll
    for (int mi = 0; mi < 8; ++mi) {
      acc[mi][2] = MFMA(a[mi], b2, acc[mi][2]);
      acc[mi][3] = MFMA(a[mi], b3, acc[mi][3]);
    }
    __builtin_amdgcn_s_setprio(0);
    asm volatile("s_waitcnt vmcnt(4)" ::: "memory");
    __builtin_amdgcn_s_barrier();

    kB += 64;
    kA += 64; if (t == 14) kA -= 1024;   // hi-segment rewind: phys(16) = 0
  }

  // ---- epilogue: acc -> bf16 C ----
  const int rq = (l >> 4) * 4;
#pragma unroll
  for (int mi = 0; mi < 8; ++mi)
#pragma unroll
    for (int ni = 0; ni < 4; ++ni) {
      int row = m0 + wr * 128 + mi * 16 + rq;
      int col = n0 + wc * 64 + ni * 16 + lr;
      unsigned short* cp = Cq + (size_t)row * N3 + col;
#pragma unroll
      for (int r = 0; r < 4; ++r)
        cp[(size_t)r * N3] = f2bf(acc[mi][ni][r]);
    }
#undef STAGE_A
#undef STAGE_B
#undef MFMA
}

// ---- per (seq, head): LN(q), LN(k), softmax(q*s @ k^T) @ v; bf16 in ----
// mode 0: write bf16 [hi|lo] rows permrow(m) into a2 (feeds pass-1 GEMM)
// mode 1: write fp32 rows permrow(m) into out (final result)
__global__ __launch_bounds__(256) void attn(const unsigned short* __restrict__ qkv,
                                            const float* __restrict__ gamma,
                                            const float* __restrict__ beta,
                                            float* __restrict__ out,
                                            unsigned short* __restrict__ a2,
                                            int mode) {
  __shared__ float q[32][65], k[32][65], v[32][65];
  __shared__ float pr[32][33];
  __shared__ float mu[64], rs[64], gm[64], bt[64];
  const int tid = threadIdx.x;
  const int s = blockIdx.x >> 4, hd = blockIdx.x & 15;
  const size_t base = (size_t)s * 32 * 3072 + hd * 64;
  if (tid < 64) { gm[tid] = gamma[tid]; bt[tid] = beta[tid]; }
  {
    const int p = tid >> 3, d0 = (tid & 7) * 8;
    size_t r = base + (size_t)p * 3072 + d0;
    u16x8 qa = *(const u16x8*)(qkv + r);
    u16x8 ka = *(const u16x8*)(qkv + r + 1024);
    u16x8 va = *(const u16x8*)(qkv + r + 2048);
#pragma unroll
    for (int j = 0; j < 8; ++j) {
      q[p][d0 + j] = bf2f(qa[j]);
      k[p][d0 + j] = bf2f(ka[j]);
      v[p][d0 + j] = bf2f(va[j]);
    }
  }
  __syncthreads();
  {  // LN stats: 64 rows (q 0-31, k 32-63) x 4 threads each
    const int r = tid >> 2, qt = tid & 3;
    const float* row = (r < 32) ? q[r] : k[r - 32];
    float s1 = 0.f, s2 = 0.f;
#pragma unroll
    for (int d = qt * 16; d < qt * 16 + 16; ++d) { float x = row[d]; s1 += x; s2 += x * x; }
    s1 += __shfl_xor(s1, 1); s2 += __shfl_xor(s2, 1);
    s1 += __shfl_xor(s1, 2); s2 += __shfl_xor(s2, 2);
    if (qt == 0) {
      float m = s1 * 0.015625f;
      mu[r] = m;
      rs[r] = rsqrtf(s2 * 0.015625f - m * m + 1e-5f);
    }
  }
  __syncthreads();
  {
    const int p = tid >> 3, d0 = (tid & 7) * 8;
#pragma unroll
    for (int j = 0; j < 8; ++j) {
      int d = d0 + j;
      q[p][d] = ((q[p][d] - mu[p]) * rs[p] * gm[d] + bt[d]) * SCALE;
      k[p][d] = (k[p][d] - mu[32 + p]) * rs[32 + p] * gm[d] + bt[d];
    }
  }
  __syncthreads();
  {  // logits: 4 per thread
    const int r = tid >> 3, c0 = (tid & 7) * 4;
#pragma unroll
    for (int cc = 0; cc < 4; ++cc) {
      float a = 0.f;
      const float* qr = q[r]; const float* kr = k[c0 + cc];
#pragma unroll
      for (int d = 0; d < 64; ++d) a += qr[d] * kr[d];
      pr[r][c0 + cc] = a;
    }
  }
  __syncthreads();
  {  // softmax: 8 threads per row
    const int r = tid >> 3, c0 = (tid & 7) * 4;
    float e0 = pr[r][c0], e1 = pr[r][c0 + 1], e2 = pr[r][c0 + 2], e3 = pr[r][c0 + 3];
    float mx = fmaxf(fmaxf(e0, e1), fmaxf(e2, e3));
    mx = fmaxf(mx, __shfl_xor(mx, 1));
    mx = fmaxf(mx, __shfl_xor(mx, 2));
    mx = fmaxf(mx, __shfl_xor(mx, 4));
    e0 = __expf(e0 - mx); e1 = __expf(e1 - mx);
    e2 = __expf(e2 - mx); e3 = __expf(e3 - mx);
    float sum = e0 + e1 + e2 + e3;
    sum += __shfl_xor(sum, 1);
    sum += __shfl_xor(sum, 2);
    sum += __shfl_xor(sum, 4);
    float inv = 1.f / sum;
    pr[r][c0] = e0 * inv; pr[r][c0 + 1] = e1 * inv;
    pr[r][c0 + 2] = e2 * inv; pr[r][c0 + 3] = e3 * inv;
  }
  __syncthreads();
  {  // PV + permuted store
    const int p = tid >> 3, d0 = (tid & 7) * 8;
    float o[8] = {};
#pragma unroll
    for (int j = 0; j < 32; ++j) {
      float pj = pr[p][j];
#pragma unroll
      for (int d = 0; d < 8; ++d) o[d] += pj * v[j][d0 + d];
    }
    int pm = permrow(s * 32 + p);
    if (mode == 0) {
      u16x8 hi, lo;
#pragma unroll
      for (int d = 0; d < 8; ++d) {
        unsigned short h = f2bf(o[d]);
        hi[d] = h;
        lo[d] = f2bf(o[d] - bf2f(h));
      }
      unsigned short* dp = a2 + (size_t)pm * 2048 + hd * 64 + d0;
      *(u16x8*)dp          = hi;
      *(u16x8*)(dp + 1024) = lo;
    } else {
      float* op = out + (size_t)pm * 1024 + hd * 64 + d0;
#pragma unroll
      for (int d = 0; d < 8; ++d) op[d] = o[d];
    }
  }
}

extern "C" void kernel_launch(void* const* d_in, const int* in_sizes, int n_in,
                              void* d_out, int out_size, void* d_ws, size_t ws_size,
                              hipStream_t stream) {
  const float* x    = (const float*)d_in[0];
  const float* Wrow = (const float*)d_in[1];
  const float* Wcol = (const float*)d_in[2];
  const float* grow = (const float*)d_in[3];
  const float* brow = (const float*)d_in[4];
  const float* gcol = (const float*)d_in[5];
  const float* bcol = (const float*)d_in[6];
  float* out = (float*)d_out;

  char* ws = (char*)d_ws;
  const size_t szA2 = (size_t)MROWS * 2048 * 2;   // 67108864
  const size_t szB2 = (size_t)N3 * N3 * 2;        // 18874368
  unsigned short* A2   = (unsigned short*)ws;
  unsigned short* B2   = (unsigned short*)(ws + szA2);
  unsigned short* qkvb = (unsigned short*)(ws + szA2 + szB2);  // 16384*3072*2

  // pass 0 (rows)
  split_x<<<8192, 256, 0, stream>>>(x, A2);
  split_w<<<1536, 256, 0, stream>>>(Wrow, B2);
  gemm256<<<768, 512, 0, stream>>>(A2, B2, qkvb);
  attn<<<8192, 256, 0, stream>>>(qkvb, grow, brow, out, A2, 0);  // writes A2 (permuted)
  // pass 1 (cols)
  split_w<<<1536, 256, 0, stream>>>(Wcol, B2);
  gemm256<<<768, 512, 0, stream>>>(A2, B2, qkvb);
  attn<<<8192, 256, 0, stream>>>(qkvb, gcol, bcol, out, A2, 1);  // writes out
}